// Round 2
// baseline (393.457 us; speedup 1.0000x reference)
//
#include <hip/hip_runtime.h>
#include <cstddef>

// N=16384, D=256, V=32000, T=128, decay=0.97
namespace {
constexpr int Nn = 16384;
constexpr int Dd = 256;
constexpr int Tt = 128;
constexpr float DECAY = 0.97f;
constexpr int NB = 256;   // grid size == CU count -> all blocks co-resident
constexpr int TPB = 256;

// workspace layout (float offsets)
constexpr size_t WS_M    = 0;                        // M[j][t]      [16384][128]
constexpr size_t WS_CUMV = WS_M + (size_t)Nn * Tt;   // cumV[s][d]   [128][256]
constexpr size_t WS_H    = WS_CUMV + (size_t)Tt * Dd;// h[s]         [128]
constexpr size_t WS_U    = WS_H + Tt;                // u[d]         [256]
constexpr size_t WS_BAR  = WS_U + Dd;                // 2 uints (barrier)
}

// Grid barrier: sense via generation counter. Device-scope atomics + fences
// handle cross-XCD L2 non-coherence (release = wbL2 before arrive,
// acquire = invL2 after release observed).
__device__ __forceinline__ void grid_barrier(unsigned* cnt, unsigned* gen) {
  __syncthreads();  // all block stores issued & vmcnt-drained
  if (threadIdx.x == 0) {
    unsigned g = __hip_atomic_load(gen, __ATOMIC_RELAXED, __HIP_MEMORY_SCOPE_AGENT);
    __threadfence();  // release: write back this block's stores device-wide
    unsigned old = __hip_atomic_fetch_add(cnt, 1u, __ATOMIC_ACQ_REL, __HIP_MEMORY_SCOPE_AGENT);
    if (old == NB - 1) {
      __hip_atomic_store(cnt, 0u, __ATOMIC_RELAXED, __HIP_MEMORY_SCOPE_AGENT);
      __hip_atomic_store(gen, g + 1u, __ATOMIC_RELEASE, __HIP_MEMORY_SCOPE_AGENT);
    } else {
      while (__hip_atomic_load(gen, __ATOMIC_ACQUIRE, __HIP_MEMORY_SCOPE_AGENT) == g)
        __builtin_amdgcn_s_sleep(8);
    }
    __threadfence();  // acquire: invalidate stale L1/L2 lines on this XCD
  }
  __syncthreads();
}

__global__ __launch_bounds__(TPB) void k_fused(
    const float* __restrict__ E, const float* __restrict__ Dx,
    const float* __restrict__ Dy, const float* __restrict__ temb,
    const int* __restrict__ toks, float* __restrict__ ws,
    float* __restrict__ out) {
  float* Mg   = ws + WS_M;
  float* cumV = ws + WS_CUMV;
  float* h    = ws + WS_H;
  float* u    = ws + WS_U;
  unsigned* bar = (unsigned*)(ws + WS_BAR);

  float* xf  = out;                // x_{T-1}   [16384]
  float* yv  = out + Nn;           // ys[-1]    [16384]
  float* vs  = out + 2 * Nn;       // vs[-1]    [256]
  float* rho = out + 2 * Nn + Dd;  // rho_f     [256][16384]

  __shared__ __align__(16) float smem[32 * 64 + 32 * 128];  // As | Bs, 24 KB
  float* As = smem;            // 2048 floats
  float* Bs = smem + 32 * 64;  // 4096 floats
  __shared__ float xjl[64];
  __shared__ int s_toks[Tt];
  __shared__ float g_l[Tt];
  __shared__ float red_l[Dd];
  __shared__ float lna_l[Dd];
  __shared__ float y_l[64];

  const int tid = threadIdx.x;
  const int b = blockIdx.x;
  const int tx = tid & 15, ty = tid >> 4;
  const int lane = tid & 63, wv = tid >> 6;

  if (tid < Tt) s_toks[tid] = toks[tid];
  __syncthreads();

  // ================= P1a: cumV[s][d] = sum_{t>=s} 0.97^(128-t) v_t[d] ======
  if (b < Tt) {
    const int s = b;
    float run = 0.f, w = DECAY;
    for (int t = Tt - 1; t >= s; --t) {
      run += w * temb[(size_t)s_toks[t] * Dd + tid];
      w *= DECAY;
    }
    cumV[s * Dd + tid] = run;
  }

  // ================= P1b: M rows [b*64, b*64+64), xf, h partials ===========
  {
    const int j0 = b * 64;
    const float4* Dx4 = (const float4*)Dx;   // row stride 64 f4
    const float4* T4 = (const float4*)temb;  // row stride 64 f4
    float acc[4][8] = {};
    float4 pa[2], pb[4];
    auto loadA = [&](int ch, int i) {
      int idx = tid + i * 256, row = idx >> 3, k4 = idx & 7;
      return Dx4[(size_t)(j0 + row) * 64 + ch * 8 + k4];
    };
    auto loadB = [&](int ch, int i) {
      int idx = tid + i * 256, t = idx >> 3, k4 = idx & 7;
      return T4[(size_t)s_toks[t] * 64 + ch * 8 + k4];
    };
    pa[0] = loadA(0, 0); pa[1] = loadA(0, 1);
    pb[0] = loadB(0, 0); pb[1] = loadB(0, 1);
    pb[2] = loadB(0, 2); pb[3] = loadB(0, 3);

    for (int ch = 0; ch < 8; ++ch) {
      __syncthreads();
#pragma unroll
      for (int i = 0; i < 2; ++i) {
        int idx = tid + i * 256, row = idx >> 3, k4 = idx & 7;
        As[(k4 * 4 + 0) * 64 + row] = pa[i].x;
        As[(k4 * 4 + 1) * 64 + row] = pa[i].y;
        As[(k4 * 4 + 2) * 64 + row] = pa[i].z;
        As[(k4 * 4 + 3) * 64 + row] = pa[i].w;
      }
#pragma unroll
      for (int i = 0; i < 4; ++i) {
        int idx = tid + i * 256, t = idx >> 3, k4 = idx & 7;
        Bs[(k4 * 4 + 0) * 128 + t] = pb[i].x;
        Bs[(k4 * 4 + 1) * 128 + t] = pb[i].y;
        Bs[(k4 * 4 + 2) * 128 + t] = pb[i].z;
        Bs[(k4 * 4 + 3) * 128 + t] = pb[i].w;
      }
      __syncthreads();
      if (ch < 7) {  // issue next chunk's global loads; latency hides under FMAs
        pa[0] = loadA(ch + 1, 0); pa[1] = loadA(ch + 1, 1);
        pb[0] = loadB(ch + 1, 0); pb[1] = loadB(ch + 1, 1);
        pb[2] = loadB(ch + 1, 2); pb[3] = loadB(ch + 1, 3);
      }
#pragma unroll
      for (int kk = 0; kk < 32; ++kk) {
        float4 a = *(const float4*)&As[kk * 64 + ty * 4];
        float4 b0 = *(const float4*)&Bs[kk * 128 + tx * 8];
        float4 b1 = *(const float4*)&Bs[kk * 128 + tx * 8 + 4];
        float avv[4] = {a.x, a.y, a.z, a.w};
        float bvv[8] = {b0.x, b0.y, b0.z, b0.w, b1.x, b1.y, b1.z, b1.w};
#pragma unroll
        for (int r = 0; r < 4; ++r)
#pragma unroll
          for (int c = 0; c < 8; ++c) acc[r][c] += avv[r] * bvv[c];
      }
    }
    // relu + store M + per-thread row partials
    float rs[4];
#pragma unroll
    for (int r = 0; r < 4; ++r) {
      float s = 0.f;
#pragma unroll
      for (int c = 0; c < 8; ++c) {
        acc[r][c] = fmaxf(acc[r][c], 0.f);
        s += acc[r][c];
      }
      rs[r] = s;
      int j = j0 + ty * 4 + r;
      float4 o0 = {acc[r][0], acc[r][1], acc[r][2], acc[r][3]};
      float4 o1 = {acc[r][4], acc[r][5], acc[r][6], acc[r][7]};
      *(float4*)&Mg[(size_t)j * Tt + tx * 8] = o0;
      *(float4*)&Mg[(size_t)j * Tt + tx * 8 + 4] = o1;
    }
    // xf reduction (reuse As region: 64*17 = 1088 floats)
    __syncthreads();
    float* redx = As;
#pragma unroll
    for (int r = 0; r < 4; ++r) redx[(ty * 4 + r) * 17 + tx] = rs[r];
    __syncthreads();
    if (tid < 64) {
      float s = 0.f;
#pragma unroll
      for (int x = 0; x < 16; ++x) s += redx[tid * 17 + x];
      xjl[tid] = s;
      xf[j0 + tid] = s;
    }
    __syncthreads();
    // h[s] partials from in-register M and LDS xf (reuse Bs: 128*17 = 2176)
    float* hred = Bs;
#pragma unroll
    for (int c = 0; c < 8; ++c) {
      float p = 0.f;
#pragma unroll
      for (int r = 0; r < 4; ++r) p += acc[r][c] * xjl[ty * 4 + r];
      hred[(tx * 8 + c) * 17 + ty] = p;
    }
    __syncthreads();
    if (tid < Tt) {
      float s = 0.f;
#pragma unroll
      for (int i = 0; i < 16; ++i) s += hred[tid * 17 + i];
      atomicAdd(&h[tid], s);
    }
  }

  grid_barrier(&bar[0], &bar[1]);

  // ================= P2: lna (redundant per block), y rows, u partials =====
  {
    if (tid < Tt) g_l[tid] = h[tid];
    __syncthreads();
    if (tid == 0) {  // prefix over LDS: g[t] = x_t . x_{T-1}
      float run = 0.f;
      for (int t = 0; t < Tt; ++t) { run += g_l[t]; g_l[t] = run; }
    }
    __syncthreads();
    float a = 0.f, w = DECAY;
    for (int t = Tt - 2; t >= 0; --t) {
      a += w * g_l[t] * temb[(size_t)s_toks[t] * Dd + tid];
      w *= DECAY;
    }
    // layernorm_row (unbiased std, eps on std)
    red_l[tid] = a;
    __syncthreads();
    for (int off = 128; off > 0; off >>= 1) {
      if (tid < off) red_l[tid] += red_l[tid + off];
      __syncthreads();
    }
    float m = red_l[0] * (1.f / 256.f);
    __syncthreads();
    float c0 = a - m;
    red_l[tid] = c0 * c0;
    __syncthreads();
    for (int off = 128; off > 0; off >>= 1) {
      if (tid < off) red_l[tid] += red_l[tid + off];
      __syncthreads();
    }
    float sd = sqrtf(red_l[0] * (1.f / 255.f));
    lna_l[tid] = c0 / (sd + 1e-6f);
    __syncthreads();

    // y for own 64 rows: wave wv handles rows [wv*16, wv*16+16)
    const int j0 = b * 64;
    const float4* Dy4 = (const float4*)Dy;
    const float4* l4 = (const float4*)lna_l;
    for (int i = 0; i < 16; ++i) {
      int jl = wv * 16 + i, j = j0 + jl;
      float4 dv = Dy4[(size_t)j * 64 + lane];
      float4 lv = l4[lane];
      float accy = dv.x * lv.x + dv.y * lv.y + dv.z * lv.z + dv.w * lv.w;
#pragma unroll
      for (int off = 32; off > 0; off >>= 1) accy += __shfl_down(accy, off);
      if (lane == 0) {
        float yy = fmaxf(accy, 0.f) * fmaxf(xjl[jl], 0.f);
        y_l[jl] = yy;
        yv[j] = yy;
      }
    }
    __syncthreads();
    // u[d] partials over this block's 64 columns of E (coalesced 256B rows)
    float yj = y_l[lane];
    for (int i = 0; i < 64; ++i) {
      int d = wv * 64 + i;
      float p = E[(size_t)d * Nn + j0 + lane] * yj;
#pragma unroll
      for (int off = 32; off > 0; off >>= 1) p += __shfl_down(p, off);
      if (lane == 0) atomicAdd(&u[d], p);
    }
  }

  grid_barrier(&bar[0], &bar[1]);

  // ================= P3: v_star (block 0) + rho tiles ======================
  if (b == 0) {
    float a = u[tid];
    red_l[tid] = a;
    __syncthreads();
    for (int off = 128; off > 0; off >>= 1) {
      if (tid < off) red_l[tid] += red_l[tid + off];
      __syncthreads();
    }
    float m = red_l[0] * (1.f / 256.f);
    __syncthreads();
    float c0 = a - m;
    red_l[tid] = c0 * c0;
    __syncthreads();
    for (int off = 128; off > 0; off >>= 1) {
      if (tid < off) red_l[tid] += red_l[tid + off];
      __syncthreads();
    }
    float sd = sqrtf(red_l[0] * (1.f / 255.f));
    vs[tid] = c0 / (sd + 1e-6f);
  }

  // rho[d][j] = sum_s cumV[s][d] * M[j][s]; two 64d x 128j tiles per block
  {
    const float4* C4 = (const float4*)cumV;  // row stride 64 f4
    const float4* M4 = (const float4*)Mg;    // row stride 32 f4
    for (int tt = 2 * b; tt <= 2 * b + 1; ++tt) {
      const int d0 = (tt & 3) * 64;
      const int j0r = (tt >> 2) * 128;
      float acc[4][8] = {};
      float4 qa[2], qb[4];
      auto loadRA = [&](int ch, int i) {
        int idx = tid + i * 256, k = idx >> 4, d4 = idx & 15;
        return C4[(size_t)(ch * 32 + k) * 64 + (d0 >> 2) + d4];
      };
      auto loadRB = [&](int ch, int i) {
        int idx = tid + i * 256, j = idx >> 3, k4 = idx & 7;
        return M4[(size_t)(j0r + j) * 32 + ch * 8 + k4];
      };
      qa[0] = loadRA(0, 0); qa[1] = loadRA(0, 1);
      qb[0] = loadRB(0, 0); qb[1] = loadRB(0, 1);
      qb[2] = loadRB(0, 2); qb[3] = loadRB(0, 3);
      for (int ch = 0; ch < 4; ++ch) {
        __syncthreads();
#pragma unroll
        for (int i = 0; i < 2; ++i) {
          int idx = tid + i * 256, k = idx >> 4, d4 = idx & 15;
          *(float4*)&As[k * 64 + d4 * 4] = qa[i];
        }
#pragma unroll
        for (int i = 0; i < 4; ++i) {
          int idx = tid + i * 256, j = idx >> 3, k4 = idx & 7;
          Bs[(k4 * 4 + 0) * 128 + j] = qb[i].x;
          Bs[(k4 * 4 + 1) * 128 + j] = qb[i].y;
          Bs[(k4 * 4 + 2) * 128 + j] = qb[i].z;
          Bs[(k4 * 4 + 3) * 128 + j] = qb[i].w;
        }
        __syncthreads();
        if (ch < 3) {
          qa[0] = loadRA(ch + 1, 0); qa[1] = loadRA(ch + 1, 1);
          qb[0] = loadRB(ch + 1, 0); qb[1] = loadRB(ch + 1, 1);
          qb[2] = loadRB(ch + 1, 2); qb[3] = loadRB(ch + 1, 3);
        }
#pragma unroll
        for (int kk = 0; kk < 32; ++kk) {
          float4 a = *(const float4*)&As[kk * 64 + ty * 4];
          float4 b0 = *(const float4*)&Bs[kk * 128 + tx * 8];
          float4 b1 = *(const float4*)&Bs[kk * 128 + tx * 8 + 4];
          float avv[4] = {a.x, a.y, a.z, a.w};
          float bvv[8] = {b0.x, b0.y, b0.z, b0.w, b1.x, b1.y, b1.z, b1.w};
#pragma unroll
          for (int r = 0; r < 4; ++r)
#pragma unroll
            for (int c = 0; c < 8; ++c) acc[r][c] += avv[r] * bvv[c];
        }
      }
#pragma unroll
      for (int r = 0; r < 4; ++r) {
        int d = d0 + ty * 4 + r;
        float4 o0 = {acc[r][0], acc[r][1], acc[r][2], acc[r][3]};
        float4 o1 = {acc[r][4], acc[r][5], acc[r][6], acc[r][7]};
        *(float4*)&rho[(size_t)d * Nn + j0r + tx * 8] = o0;
        *(float4*)&rho[(size_t)d * Nn + j0r + tx * 8 + 4] = o1;
      }
    }
  }
}

extern "C" void kernel_launch(void* const* d_in, const int* in_sizes, int n_in,
                              void* d_out, int out_size, void* d_ws, size_t ws_size,
                              hipStream_t stream) {
  const float* E = (const float*)d_in[0];     // [256][16384]
  const float* Dx = (const float*)d_in[1];    // [16384][256]
  const float* Dy = (const float*)d_in[2];    // [16384][256]
  const float* temb = (const float*)d_in[3];  // [32000][256]
  const int* toks = (const int*)d_in[4];      // [128]

  float* ws = (float*)d_ws;
  float* out = (float*)d_out;

  // zero h, u, barrier (ws is poisoned 0xAA before every timed launch)
  hipMemsetAsync(ws + WS_H, 0, (Tt + Dd + 8) * sizeof(float), stream);

  k_fused<<<NB, TPB, 0, stream>>>(E, Dx, Dy, temb, toks, ws, out);
}

// Round 3
// 178.071 us; speedup vs baseline: 2.2096x; 2.2096x over previous
//
#include <hip/hip_runtime.h>
#include <cstddef>

// N=16384, D=256, V=32000, T=128, decay=0.97
namespace {
constexpr int Nn = 16384;
constexpr int Dd = 256;
constexpr int Tt = 128;
constexpr float DECAY = 0.97f;

// workspace layout (float offsets)
constexpr size_t WS_M    = 0;                         // M[j][t]      [16384][128]
constexpr size_t WS_CUMV = WS_M + (size_t)Nn * Tt;    // cumV[s][d]   [128][256]
constexpr size_t WS_H    = WS_CUMV + (size_t)Tt * Dd; // h[s]         [128]
constexpr size_t WS_LNA  = WS_H + Tt;                 // ln(a_star)   [256]
constexpr size_t WS_U    = WS_LNA + Dd;               // u = E@y      [256]
}

// ---------------------------------------------------------------------------
// K1 (mixed roles): blocks [0,128): cumV rows; blocks [128, 128+512): M-GEMM
//   M[j][t] = relu(sum_k Dx[j][k] * V[t][k]), tile 32j x 128t, K=256
//   + xf row sums + h[s] partials from in-register M (saves an 8.4MB re-read)
// LDS staging uses XOR swizzle (col ^ 8*fn(k)) to kill 8-way write conflicts.
__global__ __launch_bounds__(256) void k_p1(const float* __restrict__ Dx,
                                            const float* __restrict__ temb,
                                            const int* __restrict__ toks,
                                            float* __restrict__ Mg,
                                            float* __restrict__ cumV,
                                            float* __restrict__ h,
                                            float* __restrict__ xf) {
  __shared__ int s_toks[Tt];
  __shared__ __align__(16) float As[32 * 32];   // [k][j^swz]
  __shared__ __align__(16) float Bs[32 * 128];  // [k][t^swz]
  __shared__ float xjl[32];

  const int tid = threadIdx.x;
  const int b = blockIdx.x;
  if (tid < Tt) s_toks[tid] = toks[tid];
  __syncthreads();

  if (b < Tt) {  // ---- cumV[s][d] = sum_{t>=s} 0.97^(128-t) v_t[d] ----
    const int s = b;
    float run = 0.f, w = DECAY;
    for (int t = Tt - 1; t >= s; --t) {
      run += w * temb[(size_t)s_toks[t] * Dd + tid];
      w *= DECAY;
    }
    cumV[s * Dd + tid] = run;
    return;
  }

  // ---- GEMM tile: rows [j0, j0+32) ----
  const int j0 = (b - Tt) * 32;
  const int tx = tid & 15, ty = tid >> 4;  // micro: 2j x 8t per thread
  const float4* Dx4 = (const float4*)Dx;   // row stride 64 f4
  const float4* T4 = (const float4*)temb;  // row stride 64 f4
  float acc[2][8] = {};

  const int arow = tid >> 3, ak4 = tid & 7;  // As loader mapping
  auto loadA = [&](int ch) {
    return Dx4[(size_t)(j0 + arow) * 64 + ch * 8 + ak4];
  };
  auto loadB = [&](int ch, int i) {
    int idx = tid + i * 256, t = idx >> 3, k4 = idx & 7;
    return T4[(size_t)s_toks[t] * 64 + ch * 8 + k4];
  };
  float4 pa = loadA(0);
  float4 pb[4] = {loadB(0, 0), loadB(0, 1), loadB(0, 2), loadB(0, 3)};

  for (int ch = 0; ch < 8; ++ch) {
    __syncthreads();
    {  // As scatter: k = ak4*4+c, col = arow ^ 8*((k>>2)&3) = arow ^ 8*(ak4&3)
      const int asw = arow ^ (8 * (ak4 & 3));
      As[(ak4 * 4 + 0) * 32 + asw] = pa.x;
      As[(ak4 * 4 + 1) * 32 + asw] = pa.y;
      As[(ak4 * 4 + 2) * 32 + asw] = pa.z;
      As[(ak4 * 4 + 3) * 32 + asw] = pa.w;
    }
#pragma unroll
    for (int i = 0; i < 4; ++i) {  // Bs scatter: col = t ^ 8*(k>>2) = t ^ 8*k4
      int idx = tid + i * 256, t = idx >> 3, k4 = idx & 7;
      const int bsw = t ^ (8 * k4);
      Bs[(k4 * 4 + 0) * 128 + bsw] = pb[i].x;
      Bs[(k4 * 4 + 1) * 128 + bsw] = pb[i].y;
      Bs[(k4 * 4 + 2) * 128 + bsw] = pb[i].z;
      Bs[(k4 * 4 + 3) * 128 + bsw] = pb[i].w;
    }
    __syncthreads();
    if (ch < 7) {  // register prefetch of next chunk; hides under FMAs
      pa = loadA(ch + 1);
      pb[0] = loadB(ch + 1, 0); pb[1] = loadB(ch + 1, 1);
      pb[2] = loadB(ch + 1, 2); pb[3] = loadB(ch + 1, 3);
    }
#pragma unroll
    for (int kk = 0; kk < 32; ++kk) {
      const int sA = 8 * ((kk >> 2) & 3);
      const int sB = 8 * (kk >> 2);
      float2 a = *(const float2*)&As[kk * 32 + ((ty * 2) ^ sA)];
      float4 b0 = *(const float4*)&Bs[kk * 128 + ((tx * 8) ^ sB)];
      float4 b1 = *(const float4*)&Bs[kk * 128 + ((tx * 8) ^ sB) + 4];
      float avv[2] = {a.x, a.y};
      float bvv[8] = {b0.x, b0.y, b0.z, b0.w, b1.x, b1.y, b1.z, b1.w};
#pragma unroll
      for (int r = 0; r < 2; ++r)
#pragma unroll
        for (int c = 0; c < 8; ++c) acc[r][c] += avv[r] * bvv[c];
    }
  }

  // relu + store M + row sums
  float rs[2];
#pragma unroll
  for (int r = 0; r < 2; ++r) {
    float s = 0.f;
#pragma unroll
    for (int c = 0; c < 8; ++c) {
      acc[r][c] = fmaxf(acc[r][c], 0.f);
      s += acc[r][c];
    }
    rs[r] = s;
    int j = j0 + ty * 2 + r;
    float4 o0 = {acc[r][0], acc[r][1], acc[r][2], acc[r][3]};
    float4 o1 = {acc[r][4], acc[r][5], acc[r][6], acc[r][7]};
    *(float4*)&Mg[(size_t)j * Tt + tx * 8] = o0;
    *(float4*)&Mg[(size_t)j * Tt + tx * 8 + 4] = o1;
  }
  __syncthreads();
  float* redx = As;  // 32*17 = 544 <= 1024
#pragma unroll
  for (int r = 0; r < 2; ++r) redx[(ty * 2 + r) * 17 + tx] = rs[r];
  __syncthreads();
  if (tid < 32) {
    float s = 0.f;
#pragma unroll
    for (int x = 0; x < 16; ++x) s += redx[tid * 17 + x];
    xjl[tid] = s;
    xf[j0 + tid] = s;  // x_{T-1}
  }
  __syncthreads();
  // h[s] partials from in-register (post-relu) M
  float* hred = Bs;  // 128*17 = 2176 <= 4096
#pragma unroll
  for (int c = 0; c < 8; ++c) {
    float p = acc[0][c] * xjl[ty * 2] + acc[1][c] * xjl[ty * 2 + 1];
    hred[(tx * 8 + c) * 17 + ty] = p;
  }
  __syncthreads();
  if (tid < Tt) {
    float s = 0.f;
#pragma unroll
    for (int i = 0; i < 16; ++i) s += hred[tid * 17 + i];
    atomicAdd(&h[tid], s);
  }
}

// ---------------------------------------------------------------------------
// K2: parallel prefix of h -> g; a_star[d] = sum_{t<=T-2} 0.97^(T-1-t) g[t] V[t][d]; LN
__global__ __launch_bounds__(256) void k_astar(const float* __restrict__ h,
                                               const float* __restrict__ temb,
                                               const int* __restrict__ toks,
                                               float* __restrict__ lna) {
  __shared__ float g[Tt];
  __shared__ float red[Dd];
  __shared__ int s_toks[Tt];
  const int d = threadIdx.x;
  if (d < Tt) {
    s_toks[d] = toks[d];
    g[d] = h[d];
  }
  __syncthreads();
  // inclusive scan (Hillis-Steele): g[t] = x_t . x_{T-1}
  for (int off = 1; off < Tt; off <<= 1) {
    float v = 0.f;
    bool act = (d < Tt) && (d >= off);
    if (act) v = g[d - off];
    __syncthreads();
    if (act) g[d] += v;
    __syncthreads();
  }
  float a = 0.f, w = DECAY;
  for (int t = Tt - 2; t >= 0; --t) {
    a += w * g[t] * temb[(size_t)s_toks[t] * Dd + d];
    w *= DECAY;
  }
  // layernorm_row (unbiased std, eps on std)
  red[d] = a;
  __syncthreads();
  for (int off = 128; off > 0; off >>= 1) {
    if (d < off) red[d] += red[d + off];
    __syncthreads();
  }
  float m = red[0] * (1.f / 256.f);
  __syncthreads();
  float c0 = a - m;
  red[d] = c0 * c0;
  __syncthreads();
  for (int off = 128; off > 0; off >>= 1) {
    if (d < off) red[d] += red[d + off];
    __syncthreads();
  }
  float sd = sqrtf(red[0] * (1.f / 255.f));
  lna[d] = c0 / (sd + 1e-6f);
}

// ---------------------------------------------------------------------------
// K3: y[j] = relu(Dy[j].lna) * max(x[j],0)   (one wave per row)
__global__ void k_y(const float* __restrict__ Dy, const float* __restrict__ lna,
                    const float* __restrict__ x, float* __restrict__ yout) {
  const int tid = threadIdx.x;
  const int wave = tid >> 6, lane = tid & 63;
  const int j = blockIdx.x * 4 + wave;
  const float4* Dy4 = (const float4*)Dy;
  const float4* l4 = (const float4*)lna;
  float4 a = Dy4[(size_t)j * 64 + lane];
  float4 bq = l4[lane];
  float acc = a.x * bq.x + a.y * bq.y + a.z * bq.z + a.w * bq.w;
#pragma unroll
  for (int off = 32; off > 0; off >>= 1) acc += __shfl_down(acc, off);
  if (lane == 0) yout[j] = fmaxf(acc, 0.f) * fmaxf(x[j], 0.f);
}

// ---------------------------------------------------------------------------
// K4: u[d] = E[d] . y   (one block per d-row, streaming coalesced)
__global__ void k_u(const float* __restrict__ E, const float* __restrict__ y,
                    float* __restrict__ u) {
  __shared__ float red[256];
  const int d = blockIdx.x, tid = threadIdx.x;
  const float4* E4 = (const float4*)E;
  const float4* y4 = (const float4*)y;
  float acc = 0.f;
  for (int i = 0; i < 16; ++i) {
    int idx = tid + i * 256;  // 4096 f4 per row
    float4 e = E4[(size_t)d * 4096 + idx];
    float4 yv = y4[idx];
    acc += e.x * yv.x + e.y * yv.y + e.z * yv.z + e.w * yv.w;
  }
  red[tid] = acc;
  __syncthreads();
  for (int off = 128; off > 0; off >>= 1) {
    if (tid < off) red[tid] += red[tid + off];
    __syncthreads();
  }
  if (tid == 0) u[d] = red[0];
}

// ---------------------------------------------------------------------------
// K5: rho[d][j] = sum_s cumV[s][d] * M[j][s]; 64d x 128j tile/block, 512 blocks
//     block 0 also computes vs = ln_row(u) first (hidden behind other blocks)
__global__ __launch_bounds__(256) void k_rho(const float* __restrict__ cumV,
                                             const float* __restrict__ Mg,
                                             const float* __restrict__ u,
                                             float* __restrict__ rho,
                                             float* __restrict__ vs) {
  __shared__ __align__(16) float As[32 * 64];   // [k][d] (no swizzle needed)
  __shared__ __align__(16) float Bs[32 * 128];  // [k][j^swz]
  __shared__ float red[Dd];
  const int tid = threadIdx.x;
  const int b = blockIdx.x;

  if (b == 0) {  // vs = ln_row(u)
    float a = u[tid];
    red[tid] = a;
    __syncthreads();
    for (int off = 128; off > 0; off >>= 1) {
      if (tid < off) red[tid] += red[tid + off];
      __syncthreads();
    }
    float m = red[0] * (1.f / 256.f);
    __syncthreads();
    float c0 = a - m;
    red[tid] = c0 * c0;
    __syncthreads();
    for (int off = 128; off > 0; off >>= 1) {
      if (tid < off) red[tid] += red[tid + off];
      __syncthreads();
    }
    float sd = sqrtf(red[0] * (1.f / 255.f));
    vs[tid] = c0 / (sd + 1e-6f);
  }

  const int d0 = (b & 3) * 64;
  const int j0 = (b >> 2) * 128;
  const int tx = tid & 15, ty = tid >> 4;  // micro: 4d x 8j
  float acc[4][8] = {};
  const float4* C4 = (const float4*)cumV;  // row stride 64 f4
  const float4* M4 = (const float4*)Mg;    // row stride 32 f4
  const int ak = tid >> 4, ad4 = tid & 15;
  auto loadRA = [&](int ch, int i) {
    return C4[(size_t)(ch * 32 + ak + i * 16) * 64 + (d0 >> 2) + ad4];
  };
  auto loadRB = [&](int ch, int i) {
    int idx = tid + i * 256, j = idx >> 3, k4 = idx & 7;
    return M4[(size_t)(j0 + j) * 32 + ch * 8 + k4];
  };
  float4 qa[2] = {loadRA(0, 0), loadRA(0, 1)};
  float4 qb[4] = {loadRB(0, 0), loadRB(0, 1), loadRB(0, 2), loadRB(0, 3)};

  for (int ch = 0; ch < 4; ++ch) {
    __syncthreads();
#pragma unroll
    for (int i = 0; i < 2; ++i)  // As: f4 write, naturally spread banks
      *(float4*)&As[(ak + i * 16) * 64 + ad4 * 4] = qa[i];
#pragma unroll
    for (int i = 0; i < 4; ++i) {  // Bs scatter with swizzle
      int idx = tid + i * 256, j = idx >> 3, k4 = idx & 7;
      const int bsw = j ^ (8 * k4);
      Bs[(k4 * 4 + 0) * 128 + bsw] = qb[i].x;
      Bs[(k4 * 4 + 1) * 128 + bsw] = qb[i].y;
      Bs[(k4 * 4 + 2) * 128 + bsw] = qb[i].z;
      Bs[(k4 * 4 + 3) * 128 + bsw] = qb[i].w;
    }
    __syncthreads();
    if (ch < 3) {
      qa[0] = loadRA(ch + 1, 0); qa[1] = loadRA(ch + 1, 1);
      qb[0] = loadRB(ch + 1, 0); qb[1] = loadRB(ch + 1, 1);
      qb[2] = loadRB(ch + 1, 2); qb[3] = loadRB(ch + 1, 3);
    }
#pragma unroll
    for (int kk = 0; kk < 32; ++kk) {
      const int sB = 8 * (kk >> 2);
      float4 a = *(const float4*)&As[kk * 64 + ty * 4];
      float4 b0 = *(const float4*)&Bs[kk * 128 + ((tx * 8) ^ sB)];
      float4 b1 = *(const float4*)&Bs[kk * 128 + ((tx * 8) ^ sB) + 4];
      float avv[4] = {a.x, a.y, a.z, a.w};
      float bvv[8] = {b0.x, b0.y, b0.z, b0.w, b1.x, b1.y, b1.z, b1.w};
#pragma unroll
      for (int r = 0; r < 4; ++r)
#pragma unroll
        for (int c = 0; c < 8; ++c) acc[r][c] += avv[r] * bvv[c];
    }
  }
#pragma unroll
  for (int r = 0; r < 4; ++r) {
    int d = d0 + ty * 4 + r;
    float4 o0 = {acc[r][0], acc[r][1], acc[r][2], acc[r][3]};
    float4 o1 = {acc[r][4], acc[r][5], acc[r][6], acc[r][7]};
    *(float4*)&rho[(size_t)d * Nn + j0 + tx * 8] = o0;
    *(float4*)&rho[(size_t)d * Nn + j0 + tx * 8 + 4] = o1;
  }
}

// ---------------------------------------------------------------------------
extern "C" void kernel_launch(void* const* d_in, const int* in_sizes, int n_in,
                              void* d_out, int out_size, void* d_ws, size_t ws_size,
                              hipStream_t stream) {
  const float* E = (const float*)d_in[0];     // [256][16384]
  const float* Dx = (const float*)d_in[1];    // [16384][256]
  const float* Dy = (const float*)d_in[2];    // [16384][256]
  const float* temb = (const float*)d_in[3];  // [32000][256]
  const int* toks = (const int*)d_in[4];      // [128]

  float* ws = (float*)d_ws;
  float* out = (float*)d_out;
  float* Mg   = ws + WS_M;
  float* cumV = ws + WS_CUMV;
  float* h    = ws + WS_H;
  float* lna  = ws + WS_LNA;
  float* u    = ws + WS_U;

  float* xf  = out;                // x_{T-1}   [16384]
  float* yv  = out + Nn;           // ys[-1]    [16384]
  float* vs  = out + 2 * Nn;       // vs[-1]    [256]
  float* rho = out + 2 * Nn + Dd;  // rho_f     [256][16384]

  hipMemsetAsync(h, 0, (Tt + 2 * Dd) * sizeof(float), stream);  // h, lna, u

  k_p1<<<Tt + Nn / 32, 256, 0, stream>>>(Dx, temb, toks, Mg, cumV, h, xf);
  k_astar<<<1, 256, 0, stream>>>(h, temb, toks, lna);
  k_y<<<Nn / 4, 256, 0, stream>>>(Dy, lna, xf, yv);
  k_u<<<Dd, 256, 0, stream>>>(E, yv, u);
  k_rho<<<512, 256, 0, stream>>>(cumV, Mg, u, rho, vs);
}